// Round 2
// baseline (234.358 us; speedup 1.0000x reference)
//
#include <hip/hip_runtime.h>
#include <hip/hip_bf16.h>

#define BB 1024
#define CC 128
#define DD 16
#define SS 4
#define OO 4
#define NK3 23
#define NK2 5
#define NK1 2

typedef unsigned int uint;
typedef unsigned short ushort;

__device__ __forceinline__ float bflo(uint u){ return __uint_as_float(u << 16); }
__device__ __forceinline__ float bfhi(uint u){ return __uint_as_float(u & 0xffff0000u); }

// ---------------- kernel 0: sort nodes by species ----------------
__global__ void sort_kernel(const int* __restrict__ sp, int* __restrict__ sorted,
                            int* __restrict__ seg) {
  __shared__ int cnt[SS];
  __shared__ int base[SS + 1];
  int t = threadIdx.x;  // 1024 threads
  if (t < SS) cnt[t] = 0;
  __syncthreads();
  int s = sp[t];
  int pos = atomicAdd(&cnt[s], 1);
  __syncthreads();
  if (t == 0) {
    base[0] = 0;
    for (int q = 0; q < SS; q++) base[q + 1] = base[q] + cnt[q];
    for (int q = 0; q <= SS; q++) seg[q] = base[q];
  }
  __syncthreads();
  sorted[base[s] + pos] = t;
}

// ---------------- kernel 1b: fold w3 into u3 basis ----------------
// uw3[s][c][o][i][j][l] (bf16) = sum_k u3_g[o_g,i,j,l,k] * w3[g,s,k,c]
// grid 512 = s(4) x o(4) x i(16) x ch(2); 256 threads = jl
__global__ __launch_bounds__(256, 2) void fold3_kernel(
    const float* __restrict__ u3_0, const float* __restrict__ u3_1,
    const float* __restrict__ w3, __hip_bfloat16* __restrict__ uw3) {
  int bx = blockIdx.x;
  int ch = bx & 1;
  int i  = (bx >> 1) & 15;
  int o  = (bx >> 5) & 3;
  int s  = bx >> 7;
  int g  = (o > 0) ? 1 : 0;
  int og = g ? (o - 1) : 0;
  const float* u3 = g ? u3_1 : u3_0;

  __shared__ float u3s[5888];        // (j,l,k) slice, 23.5 KB
  __shared__ float w3s[NK3 * 64];    // w3[k][c'], 5.9 KB
  int tid = threadIdx.x;

  // stage u3 slice (o_g, i): 5888 floats contiguous = 1472 float4
  const float4* u3p = (const float4*)(u3 + (size_t)(og * 16 + i) * 5888);
  for (int d = tid; d < 1472; d += 256) {
    float4 v = u3p[d];
    u3s[4 * d]     = v.x;
    u3s[4 * d + 1] = v.y;
    u3s[4 * d + 2] = v.z;
    u3s[4 * d + 3] = v.w;
  }
  // stage w3 columns
  for (int t = tid; t < NK3 * 64; t += 256) {
    int k = t >> 6, cp = t & 63;
    w3s[t] = w3[((size_t)(g * SS + s) * NK3 + k) * CC + ch * 64 + cp];
  }
  __syncthreads();

  float acc[64];
  #pragma unroll
  for (int q = 0; q < 64; q++) acc[q] = 0.f;
  int jl = tid;
  for (int k = 0; k < NK3; k++) {
    float u3v = u3s[jl * NK3 + k];           // stride 23: conflict-free
    const float4* wp = (const float4*)&w3s[k * 64];
    #pragma unroll
    for (int cq = 0; cq < 16; cq++) {
      float4 wv = wp[cq];                     // uniform broadcast
      acc[cq * 4 + 0] = fmaf(u3v, wv.x, acc[cq * 4 + 0]);
      acc[cq * 4 + 1] = fmaf(u3v, wv.y, acc[cq * 4 + 1]);
      acc[cq * 4 + 2] = fmaf(u3v, wv.z, acc[cq * 4 + 2]);
      acc[cq * 4 + 3] = fmaf(u3v, wv.w, acc[cq * 4 + 3]);
    }
  }
  // store: lane-contiguous over jl for each c'
  #pragma unroll
  for (int cp = 0; cp < 64; cp++) {
    size_t e = ((((size_t)(s * CC + ch * 64 + cp) * OO + o) * DD + i) * 256) + jl;
    uw3[e] = __float2bfloat16(acc[cp]);
  }
}

// ---------------- kernel 1c: fold w2/w1 ----------------
// grid 512 = (s,c); 256 threads = (o,i,jq)
__global__ __launch_bounds__(256, 2) void fold21_kernel(
    const float* __restrict__ u2_0, const float* __restrict__ u2_1,
    const float* __restrict__ u1_0, const float* __restrict__ u1_1,
    const float* __restrict__ w2,  const float* __restrict__ w1,
    float* __restrict__ uw2, float* __restrict__ uw1) {
  int bx = blockIdx.x;
  int s = bx >> 7, c = bx & 127;
  int tid = threadIdx.x;
  int o = tid >> 6, i = (tid >> 2) & 15, jq = tid & 3;
  int g = (o > 0) ? 1 : 0;
  int og = g ? (o - 1) : 0;
  const float* u2 = g ? u2_1 : u2_0;

  float w2c[NK2];
  #pragma unroll
  for (int k = 0; k < NK2; k++)
    w2c[k] = w2[((size_t)(g * SS + s) * NK2 + k) * CC + c];

  float4 outv;
  float* op = (float*)&outv;
  #pragma unroll
  for (int jj = 0; jj < 4; jj++) {
    int j = jq * 4 + jj;
    float a = 0.f;
    #pragma unroll
    for (int k = 0; k < NK2; k++)
      a = fmaf(u2[((size_t)(og * 16 + i) * 16 + j) * NK2 + k], w2c[k], a);
    op[jj] = a;
  }
  *(float4*)(uw2 + ((((size_t)(s * CC + c) * OO + o) * DD + i) * DD + jq * 4)) = outv;

  if (tid < 64) {
    int o2 = tid >> 4, i2 = tid & 15;
    int g2 = (o2 > 0) ? 1 : 0;
    int og2 = g2 ? (o2 - 1) : 0;
    const float* u1 = g2 ? u1_1 : u1_0;
    float a = 0.f;
    #pragma unroll
    for (int k = 0; k < NK1; k++)
      a = fmaf(u1[(size_t)(og2 * 16 + i2) * NK1 + k],
               w1[((size_t)(g2 * SS + s) * NK1 + k) * CC + c], a);
    uw1[(((size_t)(s * CC + c) * OO + o2) * DD) + i2] = a;
  }
}

// ---------------- kernel 2: main symmetric contraction ----------------
// grid 512 = (s,c); 256 threads = 4 waves (o) x 64 lanes (i=lane>>2, jq=lane&3)
__global__ __launch_bounds__(256, 2) void corr_kernel(
    const float* __restrict__ xg, const __hip_bfloat16* __restrict__ uw3,
    const float* __restrict__ uw2, const float* __restrict__ uw1,
    const int* __restrict__ sorted, const int* __restrict__ seg,
    float* __restrict__ y) {
  int bx = blockIdx.x;
  int s = bx >> 7, c = bx & 127;
  int tid = threadIdx.x;
  int o = tid >> 6;
  int lane = tid & 63;
  int i = lane >> 2, jq = lane & 3;

  // uw3 fragment: 64 bf16 per lane, lane-contiguous 128B
  size_t base3 = (((size_t)(s * CC + c) * OO + o) * 4096) + (size_t)lane * 64;
  const uint4* p3 = (const uint4*)(uw3 + base3);
  float uv[64];
  #pragma unroll
  for (int q = 0; q < 8; q++) {
    uint4 vv = p3[q];
    uv[q * 8 + 0] = bflo(vv.x); uv[q * 8 + 1] = bfhi(vv.x);
    uv[q * 8 + 2] = bflo(vv.y); uv[q * 8 + 3] = bfhi(vv.y);
    uv[q * 8 + 4] = bflo(vv.z); uv[q * 8 + 5] = bfhi(vv.z);
    uv[q * 8 + 6] = bflo(vv.w); uv[q * 8 + 7] = bfhi(vv.w);
  }
  float4 w2v = ((const float4*)(uw2 + ((size_t)(s * CC + c) * OO + o) * 256))[lane];
  float uw2r[4] = {w2v.x, w2v.y, w2v.z, w2v.w};
  float uw1r = uw1[(((size_t)(s * CC + c) * OO + o) * DD) + i];

  __shared__ float xs[64][16];   // node x chunk
  int s0 = seg[s], s1 = seg[s + 1];

  for (int base = s0; base < s1; base += 64) {
    int nn = min(64, s1 - base);
    __syncthreads();
    int nl = tid >> 2, qq = tid & 3;
    if (nl < nn) {
      int b = sorted[base + nl];
      float4 v = *((const float4*)(xg + ((size_t)b * CC + c) * DD) + qq);
      xs[nl][qq * 4 + 0] = v.x;
      xs[nl][qq * 4 + 1] = v.y;
      xs[nl][qq * 4 + 2] = v.z;
      xs[nl][qq * 4 + 3] = v.w;
    }
    __syncthreads();

    for (int n = 0; n < nn; n++) {
      float xv[16];
      #pragma unroll
      for (int l = 0; l < 16; l++) xv[l] = xs[n][l];   // uniform b128 reads
      float xi = xs[n][i];
      float p = 0.f;
      #pragma unroll
      for (int jj = 0; jj < 4; jj++) {
        float v = uw2r[jj];
        #pragma unroll
        for (int l = 0; l < 16; l++) v = fmaf(uv[jj * 16 + l], xv[l], v);
        p = fmaf(v, xs[n][jq * 4 + jj], p);
      }
      // reduce over j (lane bits 0..1) -> p replicated across jq
      p += __shfl_xor(p, 1, 64);
      p += __shfl_xor(p, 2, 64);
      float t = (p + uw1r) * xi;
      // reduce over i (lane bits 2..5): each i enters exactly once per jq class
      t += __shfl_xor(t, 4, 64);
      t += __shfl_xor(t, 8, 64);
      t += __shfl_xor(t, 16, 64);
      t += __shfl_xor(t, 32, 64);
      if (lane == 0) {
        int b = sorted[base + n];
        y[(((size_t)b * CC) + c) * OO + o] = t;
      }
    }
  }
}

// ---------------- kernel 3: channel-mixing linear + pack output ----------------
// grid 512; 256 threads = 2 b x 128 n
__global__ __launch_bounds__(256, 2) void lin_kernel(
    const float* __restrict__ y, const float* __restrict__ w_lin,
    float* __restrict__ out) {
  int tid = threadIdx.x;
  int b = blockIdx.x * 2 + (tid >> 7);
  int n = tid & 127;
  const float* yb = y + (size_t)b * CC * OO;
  float a0 = 0.f, a1 = 0.f, a2 = 0.f, a3 = 0.f;
  #pragma unroll 8
  for (int cc = 0; cc < CC; cc++) {
    float4 yv = *(const float4*)(yb + cc * 4);            // uniform within wave-half
    float wl0 = w_lin[(size_t)cc * CC + n];               // g=0
    float wl1 = w_lin[16384 + (size_t)cc * CC + n];       // g=1
    a0 = fmaf(yv.x, wl0, a0);
    a1 = fmaf(yv.y, wl1, a1);
    a2 = fmaf(yv.z, wl1, a2);
    a3 = fmaf(yv.w, wl1, a3);
  }
  const float scale = 0.08838834764831845f;  // 1/sqrt(128)
  out[(size_t)b * 512 + n] = a0 * scale;
  out[(size_t)b * 512 + 128 + (size_t)n * 3 + 0] = a1 * scale;
  out[(size_t)b * 512 + 128 + (size_t)n * 3 + 1] = a2 * scale;
  out[(size_t)b * 512 + 128 + (size_t)n * 3 + 2] = a3 * scale;
}

extern "C" void kernel_launch(void* const* d_in, const int* in_sizes, int n_in,
                              void* d_out, int out_size, void* d_ws, size_t ws_size,
                              hipStream_t stream) {
  const float* node_feats = (const float*)d_in[0];
  const float* u3_0 = (const float*)d_in[1];
  const float* u3_1 = (const float*)d_in[2];
  const float* u2_0 = (const float*)d_in[3];
  const float* u2_1 = (const float*)d_in[4];
  const float* u1_0 = (const float*)d_in[5];
  const float* u1_1 = (const float*)d_in[6];
  const float* w3   = (const float*)d_in[7];
  const float* w2   = (const float*)d_in[8];
  const float* w1   = (const float*)d_in[9];
  const float* wlin = (const float*)d_in[10];
  const int* species = (const int*)d_in[11];
  float* out = (float*)d_out;

  char* ws = (char*)d_ws;
  __hip_bfloat16* uw3 = (__hip_bfloat16*)ws;        // 16,777,216 B
  float* uw2 = (float*)(ws + 16777216);             //  2,097,152 B
  float* uw1 = (float*)(ws + 18874368);             //    131,072 B
  float* yb  = (float*)(ws + 19005440);             //  2,097,152 B
  int* sorted = (int*)(ws + 21102592);              //      4,096 B
  int* seg    = (int*)(ws + 21106688);              //         32 B

  sort_kernel<<<1, 1024, 0, stream>>>(species, sorted, seg);
  fold3_kernel<<<512, 256, 0, stream>>>(u3_0, u3_1, w3, uw3);
  fold21_kernel<<<512, 256, 0, stream>>>(u2_0, u2_1, u1_0, u1_1, w2, w1, uw2, uw1);
  corr_kernel<<<512, 256, 0, stream>>>(node_feats, uw3, uw2, uw1, sorted, seg, yb);
  lin_kernel<<<512, 256, 0, stream>>>(yb, wlin, out);
}

// Round 3
// 159.037 us; speedup vs baseline: 1.4736x; 1.4736x over previous
//
#include <hip/hip_runtime.h>
#include <hip/hip_bf16.h>

#define SS 4
#define CC 128
#define DD 16
#define OO 4
#define NK3 23
#define NK2 5
#define NK1 2
#define KTOT 288      // padded K (273 meaningful)
#define WELEM 18432   // 9 kt * 4 nt * 64 lanes * 8 bf16 per (s,c)
#define AROW 296      // A_lds row stride in bf16 (148 dwords)

typedef unsigned int uint;
typedef unsigned short ushort;
typedef __attribute__((ext_vector_type(8))) short bf16x8;
typedef __attribute__((ext_vector_type(4))) float f32x4;

__device__ __forceinline__ ushort f2bf(float f) {
  uint u = __float_as_uint(f);
  uint r = (u + 0x7fffu + ((u >> 16) & 1u)) >> 16;
  return (ushort)r;
}

// ---------------- kernel 0: sort nodes by species ----------------
__global__ void sort_kernel(const int* __restrict__ sp, int* __restrict__ sorted,
                            int* __restrict__ seg) {
  __shared__ int cnt[SS];
  __shared__ int base[SS + 1];
  int t = threadIdx.x;  // 1024 threads
  if (t < SS) cnt[t] = 0;
  __syncthreads();
  int s = sp[t];
  int pos = atomicAdd(&cnt[s], 1);
  __syncthreads();
  if (t == 0) {
    base[0] = 0;
    for (int q = 0; q < SS; q++) base[q + 1] = base[q] + cnt[q];
    for (int q = 0; q <= SS; q++) seg[q] = base[q];
  }
  __syncthreads();
  sorted[base[s] + pos] = t;
}

// ---------------- kernel 1: fold w3 into u3 -> W rows k=0..255 ----------------
// W[(s,c)][k=(j,l)][n=(o,i)] = sum_k3 u3_g[og,i,j,l,k3] * w3[g,s,k3,c]
// stored pre-swizzled in MFMA B-frag order:
//   ushort idx = (s*CC+c)*WELEM + ((kt*4+nt)*64 + lq*16 + ln)*8 + t
//   where k = kt*32+lq*8+t, n = nt*16+ln
// grid 512 = s(4) x o(4) x i(16) x ch(2); 256 threads = jl = k
__global__ __launch_bounds__(256, 2) void fold3_kernel(
    const float* __restrict__ u3_0, const float* __restrict__ u3_1,
    const float* __restrict__ w3, ushort* __restrict__ W) {
  int bx = blockIdx.x;
  int ch = bx & 1;
  int i  = (bx >> 1) & 15;
  int o  = (bx >> 5) & 3;
  int s  = bx >> 7;
  int g  = (o > 0) ? 1 : 0;
  int og = g ? (o - 1) : 0;
  const float* u3 = g ? u3_1 : u3_0;

  __shared__ float u3s[5888];        // (j,l,k3) slice
  __shared__ float w3s[NK3 * 64];
  int tid = threadIdx.x;

  const float4* u3p = (const float4*)(u3 + (size_t)(og * 16 + i) * 5888);
  for (int d = tid; d < 1472; d += 256) {
    float4 v = u3p[d];
    u3s[4 * d]     = v.x;
    u3s[4 * d + 1] = v.y;
    u3s[4 * d + 2] = v.z;
    u3s[4 * d + 3] = v.w;
  }
  for (int t = tid; t < NK3 * 64; t += 256) {
    int k = t >> 6, cp = t & 63;
    w3s[t] = w3[((size_t)(g * SS + s) * NK3 + k) * CC + ch * 64 + cp];
  }
  __syncthreads();

  float acc[64];
  #pragma unroll
  for (int q = 0; q < 64; q++) acc[q] = 0.f;
  int jl = tid;
  for (int k = 0; k < NK3; k++) {
    float u3v = u3s[jl * NK3 + k];
    const float4* wp = (const float4*)&w3s[k * 64];
    #pragma unroll
    for (int cq = 0; cq < 16; cq++) {
      float4 wv = wp[cq];
      acc[cq * 4 + 0] = fmaf(u3v, wv.x, acc[cq * 4 + 0]);
      acc[cq * 4 + 1] = fmaf(u3v, wv.y, acc[cq * 4 + 1]);
      acc[cq * 4 + 2] = fmaf(u3v, wv.z, acc[cq * 4 + 2]);
      acc[cq * 4 + 3] = fmaf(u3v, wv.w, acc[cq * 4 + 3]);
    }
  }
  // swizzled scatter store
  int kt = jl >> 5, lq = (jl >> 3) & 3, t7 = jl & 7;
  size_t off0 = ((size_t)(kt * 4 + o) * 64 + (size_t)lq * 16 + i) * 8 + t7;
  #pragma unroll
  for (int cp = 0; cp < 64; cp++) {
    size_t base = (size_t)(s * CC + ch * 64 + cp) * WELEM;
    W[base + off0] = f2bf(acc[cp]);
  }
}

// ---------------- kernel 2: fold w2/w1 -> W rows k=256..287 (kt=8) ----------------
// grid 512 = (s,c); 256 threads = (n=tid>>2, lq=tid&3), each writes 8 bf16 (one uint4)
__global__ void fold21_kernel(
    const float* __restrict__ u2_0, const float* __restrict__ u2_1,
    const float* __restrict__ u1_0, const float* __restrict__ u1_1,
    const float* __restrict__ w2,  const float* __restrict__ w1,
    ushort* __restrict__ W) {
  int bx = blockIdx.x;
  int s = bx >> 7, c = bx & 127;
  int tid = threadIdx.x;
  int n = tid >> 2, lq = tid & 3;
  int o = n >> 4, i = n & 15;
  int g = (o > 0) ? 1 : 0, og = g ? (o - 1) : 0;
  const float* u2 = g ? u2_1 : u2_0;
  const float* u1 = g ? u1_1 : u1_0;

  ushort vals[8];
  #pragma unroll
  for (int t = 0; t < 8; t++) {
    int k = 256 + lq * 8 + t;
    float v = 0.f;
    if (k < 272) {
      int j = k - 256;
      #pragma unroll
      for (int k2 = 0; k2 < NK2; k2++)
        v = fmaf(u2[((size_t)(og * 16 + i) * 16 + j) * NK2 + k2],
                 w2[((size_t)(g * SS + s) * NK2 + k2) * CC + c], v);
    } else if (k == 272) {
      #pragma unroll
      for (int k2 = 0; k2 < NK1; k2++)
        v = fmaf(u1[(size_t)(og * 16 + i) * NK1 + k2],
                 w1[((size_t)(g * SS + s) * NK1 + k2) * CC + c], v);
    }
    vals[t] = f2bf(v);
  }
  uint4 pk;
  pk.x = (uint)vals[0] | ((uint)vals[1] << 16);
  pk.y = (uint)vals[2] | ((uint)vals[3] << 16);
  pk.z = (uint)vals[4] | ((uint)vals[5] << 16);
  pk.w = (uint)vals[6] | ((uint)vals[7] << 16);
  size_t base = (size_t)(s * CC + c) * WELEM;
  size_t off = ((size_t)(8 * 4 + o) * 64 + (size_t)lq * 16 + i) * 8;
  *(uint4*)(W + base + off) = pk;
}

// ---------------- kernel 3: main contraction via MFMA ----------------
// grid 512 = (s,c); 4 waves; wave w handles m-tile rows [w*16, w*16+16) of each
// 64-node slab. D = A*W (16x16x32 bf16 MFMA), epilogue y[b,o] = sum_i D*x_i.
__global__ __launch_bounds__(256, 2) void corr_kernel(
    const float* __restrict__ xg, const ushort* __restrict__ Wg,
    const int* __restrict__ sorted, const int* __restrict__ seg,
    float* __restrict__ y) {
  __shared__ ushort Wl[WELEM];       // 36864 B
  __shared__ ushort Al[64 * AROW];   // 37888 B
  __shared__ float  xl[64][20];      //  5120 B
  int bx = blockIdx.x;
  int s = bx >> 7, c = bx & 127;
  int tid = threadIdx.x;
  int w = tid >> 6, lane = tid & 63;
  int lq = lane >> 4, ln = lane & 15;

  // stage W (coalesced b128 copies)
  {
    const uint4* wg4 = (const uint4*)Wg + (size_t)(s * CC + c) * (WELEM / 8);
    uint4* wl4 = (uint4*)Wl;
    for (int d = tid; d < WELEM / 8; d += 256) wl4[d] = wg4[d];
  }
  int s0 = seg[s], s1 = seg[s + 1];
  __syncthreads();

  for (int base = s0; base < s1; base += 64) {
    int nn = min(64, s1 - base);
    __syncthreads();  // previous epilogue done reading xl
    // stage x (fp32), zero tail rows
    {
      int n = tid >> 2, q = tid & 3;
      float4 v = make_float4(0.f, 0.f, 0.f, 0.f);
      if (n < nn)
        v = *((const float4*)(xg + ((size_t)sorted[base + n] * CC + c) * DD) + q);
      *(float4*)(&xl[n][q * 4]) = v;
    }
    __syncthreads();
    // build A rows: [P(256) | x(16) | 1 | zeros]
    {
      int n = tid >> 2, q = tid & 3;
      float xv[16];
      #pragma unroll
      for (int l = 0; l < 16; l++) xv[l] = xl[n][l];
      uint* arow = (uint*)Al + n * (AROW / 2);
      #pragma unroll
      for (int wq = 0; wq < 8; wq++) {
        uint4 pk;
        uint* pp = (uint*)&pk;
        #pragma unroll
        for (int e = 0; e < 4; e++) {
          int jl0 = q * 64 + wq * 8 + e * 2;
          int j0 = jl0 >> 4, l0 = jl0 & 15;
          pp[e] = (uint)f2bf(xv[j0] * xv[l0]) | ((uint)f2bf(xv[j0] * xv[l0 + 1]) << 16);
        }
        *(uint4*)(arow + q * 32 + wq * 4) = pk;
      }
      // tail dwords 128..147 (cols 256..295)
      #pragma unroll
      for (int dq = 0; dq < 5; dq++) {
        int d = 128 + q * 5 + dq;
        uint val = 0u;
        if (d < 136) {
          int p = d - 128;
          val = (uint)f2bf(xv[2 * p]) | ((uint)f2bf(xv[2 * p + 1]) << 16);
        } else if (d == 136) {
          val = 0x3f80u;  // (bf16)1.0 in low half, 0 in high
        }
        arow[d] = val;
      }
    }
    __syncthreads();
    // MFMA over K: 9 kt-steps x 4 n-tiles
    f32x4 acc[4];
    #pragma unroll
    for (int nt = 0; nt < 4; nt++) acc[nt] = (f32x4){0.f, 0.f, 0.f, 0.f};
    #pragma unroll
    for (int kt = 0; kt < 9; kt++) {
      uint4 av = *(const uint4*)((uint*)Al + (w * 16 + ln) * (AROW / 2) + kt * 16 + lq * 4);
      bf16x8 a = *(bf16x8*)&av;
      #pragma unroll
      for (int nt = 0; nt < 4; nt++) {
        uint4 bv = *((const uint4*)Wl + (kt * 4 + nt) * 64 + lane);
        bf16x8 b = *(bf16x8*)&bv;
        acc[nt] = __builtin_amdgcn_mfma_f32_16x16x32_bf16(a, b, acc[nt], 0, 0, 0);
      }
    }
    // epilogue: y[b,o] = sum_i D[m][(o,i)] * x[m][i]
    #pragma unroll
    for (int nt = 0; nt < 4; nt++) {
      #pragma unroll
      for (int r = 0; r < 4; r++) {
        int m = lq * 4 + r;
        float v = acc[nt][r] * xl[w * 16 + m][ln];
        v += __shfl_xor(v, 1, 64);
        v += __shfl_xor(v, 2, 64);
        v += __shfl_xor(v, 4, 64);
        v += __shfl_xor(v, 8, 64);
        int grow = w * 16 + m;
        if (ln == 0 && grow < nn) {
          int b = sorted[base + grow];
          y[((size_t)b * CC + c) * OO + nt] = v;
        }
      }
    }
  }
}

// ---------------- kernel 4: channel-mixing linear + pack output ----------------
// grid 512; 256 threads = 2 b x 128 n
__global__ __launch_bounds__(256, 2) void lin_kernel(
    const float* __restrict__ y, const float* __restrict__ w_lin,
    float* __restrict__ out) {
  int tid = threadIdx.x;
  int b = blockIdx.x * 2 + (tid >> 7);
  int n = tid & 127;
  const float* yb = y + (size_t)b * CC * OO;
  float a0 = 0.f, a1 = 0.f, a2 = 0.f, a3 = 0.f;
  #pragma unroll 8
  for (int cc = 0; cc < CC; cc++) {
    float4 yv = *(const float4*)(yb + cc * 4);
    float wl0 = w_lin[(size_t)cc * CC + n];
    float wl1 = w_lin[16384 + (size_t)cc * CC + n];
    a0 = fmaf(yv.x, wl0, a0);
    a1 = fmaf(yv.y, wl1, a1);
    a2 = fmaf(yv.z, wl1, a2);
    a3 = fmaf(yv.w, wl1, a3);
  }
  const float scale = 0.08838834764831845f;  // 1/sqrt(128)
  out[(size_t)b * 512 + n] = a0 * scale;
  out[(size_t)b * 512 + 128 + (size_t)n * 3 + 0] = a1 * scale;
  out[(size_t)b * 512 + 128 + (size_t)n * 3 + 1] = a2 * scale;
  out[(size_t)b * 512 + 128 + (size_t)n * 3 + 2] = a3 * scale;
}

extern "C" void kernel_launch(void* const* d_in, const int* in_sizes, int n_in,
                              void* d_out, int out_size, void* d_ws, size_t ws_size,
                              hipStream_t stream) {
  const float* node_feats = (const float*)d_in[0];
  const float* u3_0 = (const float*)d_in[1];
  const float* u3_1 = (const float*)d_in[2];
  const float* u2_0 = (const float*)d_in[3];
  const float* u2_1 = (const float*)d_in[4];
  const float* u1_0 = (const float*)d_in[5];
  const float* u1_1 = (const float*)d_in[6];
  const float* w3   = (const float*)d_in[7];
  const float* w2   = (const float*)d_in[8];
  const float* w1   = (const float*)d_in[9];
  const float* wlin = (const float*)d_in[10];
  const int* species = (const int*)d_in[11];
  float* out = (float*)d_out;

  char* ws = (char*)d_ws;
  ushort* W  = (ushort*)ws;                  // 512*36864 = 18,874,368 B
  float* yb  = (float*)(ws + 18874368);      //  2,097,152 B
  int* sorted = (int*)(ws + 20971520);       //      4,096 B
  int* seg    = (int*)(ws + 20975616);       //         32 B

  sort_kernel<<<1, 1024, 0, stream>>>(species, sorted, seg);
  fold3_kernel<<<512, 256, 0, stream>>>(u3_0, u3_1, w3, W);
  fold21_kernel<<<512, 256, 0, stream>>>(u2_0, u2_1, u1_0, u1_1, w2, w1, W);
  corr_kernel<<<512, 256, 0, stream>>>(node_feats, W, sorted, seg, yb);
  lin_kernel<<<512, 256, 0, stream>>>(yb, wlin, out);
}

// Round 4
// 129.449 us; speedup vs baseline: 1.8104x; 1.2286x over previous
//
#include <hip/hip_runtime.h>
#include <hip/hip_bf16.h>

#define SS 4
#define CC 128
#define WELEM 18432   // per-(s,c) W chunk, bf16 elems: 16384 main [n][jl] + 2048 tail (B-frag)
#define NK3 23
#define NK2 5
#define NK1 2

typedef unsigned int uint;
typedef unsigned short ushort;
typedef __attribute__((ext_vector_type(8))) short bf16x8;
typedef __attribute__((ext_vector_type(4))) float f32x4;

__device__ __forceinline__ ushort f2bf(float f) {
  uint u = __float_as_uint(f);
  return (ushort)((u + 0x7fffu + ((u >> 16) & 1u)) >> 16);
}
__device__ __forceinline__ uint pk2(float a, float b) {
  __hip_bfloat162 h = __float22bfloat162_rn(make_float2(a, b));  // v_cvt_pk_bf16_f32
  return *(uint*)&h;
}

// ============ pre_kernel: fold3 (blocks 0..511) + fold21 (512..1023) + sort (1024) ============
__global__ __launch_bounds__(256) void pre_kernel(
    const float* __restrict__ u3_0, const float* __restrict__ u3_1,
    const float* __restrict__ w3,
    const float* __restrict__ u2_0, const float* __restrict__ u2_1,
    const float* __restrict__ u1_0, const float* __restrict__ u1_1,
    const float* __restrict__ w2,  const float* __restrict__ w1,
    const int* __restrict__ sp, ushort* __restrict__ W,
    int* __restrict__ sorted, int* __restrict__ seg) {
  __shared__ float smem[5888 + NK3 * 64];
  int bx = blockIdx.x;
  int tid = threadIdx.x;

  if (bx < 512) {
    // ---- fold3: W main, linear layout [s][c][n=o*16+i][jl], coalesced stores ----
    float* u3s = smem;            // 5888 floats
    float* w3s = smem + 5888;     // 23*64 floats
    int ch = bx & 1, i = (bx >> 1) & 15, o = (bx >> 5) & 3, s = bx >> 7;
    int g = (o > 0) ? 1 : 0, og = g ? (o - 1) : 0;
    const float* u3 = g ? u3_1 : u3_0;

    const float4* u3p = (const float4*)(u3 + (size_t)(og * 16 + i) * 5888);
    for (int d = tid; d < 1472; d += 256) {
      float4 v = u3p[d];
      u3s[4 * d] = v.x; u3s[4 * d + 1] = v.y; u3s[4 * d + 2] = v.z; u3s[4 * d + 3] = v.w;
    }
    for (int t = tid; t < NK3 * 64; t += 256) {
      int k = t >> 6, cp = t & 63;
      w3s[t] = w3[((size_t)(g * SS + s) * NK3 + k) * CC + ch * 64 + cp];
    }
    __syncthreads();

    float acc[64];
    #pragma unroll
    for (int q = 0; q < 64; q++) acc[q] = 0.f;
    int jl = tid;
    for (int k = 0; k < NK3; k++) {
      float u3v = u3s[jl * NK3 + k];
      const float4* wp = (const float4*)&w3s[k * 64];
      #pragma unroll
      for (int cq = 0; cq < 16; cq++) {
        float4 wv = wp[cq];
        acc[cq * 4 + 0] = fmaf(u3v, wv.x, acc[cq * 4 + 0]);
        acc[cq * 4 + 1] = fmaf(u3v, wv.y, acc[cq * 4 + 1]);
        acc[cq * 4 + 2] = fmaf(u3v, wv.z, acc[cq * 4 + 2]);
        acc[cq * 4 + 3] = fmaf(u3v, wv.w, acc[cq * 4 + 3]);
      }
    }
    int n = o * 16 + i;
    #pragma unroll
    for (int cp = 0; cp < 64; cp++) {
      W[(size_t)(s * CC + ch * 64 + cp) * WELEM + n * 256 + jl] = f2bf(acc[cp]);
    }
  } else if (bx < 1024) {
    // ---- fold21: W tail (k=256..287), stored directly in B-frag layout ----
    int b2 = bx - 512;
    int s = b2 >> 7, c = b2 & 127;
    int n = tid >> 2, lq = tid & 3;
    int o = n >> 4, i = n & 15;
    int g = (o > 0) ? 1 : 0, og = g ? (o - 1) : 0;
    const float* u2 = g ? u2_1 : u2_0;
    const float* u1 = g ? u1_1 : u1_0;

    float vals[8];
    #pragma unroll
    for (int t = 0; t < 8; t++) {
      int k = 256 + lq * 8 + t;
      float v = 0.f;
      if (k < 272) {
        int j = k - 256;
        #pragma unroll
        for (int k2 = 0; k2 < NK2; k2++)
          v = fmaf(u2[((size_t)(og * 16 + i) * 16 + j) * NK2 + k2],
                   w2[((size_t)(g * SS + s) * NK2 + k2) * CC + c], v);
      } else if (k == 272) {
        #pragma unroll
        for (int k2 = 0; k2 < NK1; k2++)
          v = fmaf(u1[(size_t)(og * 16 + i) * NK1 + k2],
                   w1[((size_t)(g * SS + s) * NK1 + k2) * CC + c], v);
      }
      vals[t] = v;
    }
    uint4 pk;
    pk.x = pk2(vals[0], vals[1]); pk.y = pk2(vals[2], vals[3]);
    pk.z = pk2(vals[4], vals[5]); pk.w = pk2(vals[6], vals[7]);
    size_t base = (size_t)(s * CC + c) * WELEM;
    size_t off = 16384 + ((size_t)o * 64 + lq * 16 + i) * 8;
    *(uint4*)(W + base + off) = pk;
  } else {
    // ---- sort nodes by species ----
    __shared__ int cnt[SS];
    __shared__ int basep[SS + 1];
    if (tid < SS) cnt[tid] = 0;
    __syncthreads();
    int mysp[4], mypos[4];
    #pragma unroll
    for (int q = 0; q < 4; q++) {
      int node = q * 256 + tid;
      int s = sp[node];
      mysp[q] = s;
      mypos[q] = atomicAdd(&cnt[s], 1);
    }
    __syncthreads();
    if (tid == 0) {
      basep[0] = 0;
      for (int q = 0; q < SS; q++) basep[q + 1] = basep[q] + cnt[q];
      for (int q = 0; q <= SS; q++) seg[q] = basep[q];
    }
    __syncthreads();
    #pragma unroll
    for (int q = 0; q < 4; q++)
      sorted[basep[mysp[q]] + mypos[q]] = q * 256 + tid;
  }
}

// ============ corr_kernel: MFMA symmetric contraction ============
// grid 512 = (s,c); 4 waves; wave w owns rows [w*16, w*16+16) of each 64-node slab.
// A built in registers from xv; B: kt0..2 reg-cached, kt3..8 in LDS (xor-swizzled).
__global__ __launch_bounds__(256, 2) void corr_kernel(
    const float* __restrict__ xg, const ushort* __restrict__ Wg,
    const int* __restrict__ sorted, const int* __restrict__ seg,
    float* __restrict__ y) {
  __shared__ uint4 Wl4[1536];          // 24 KB: spans 0..19 = kt3..7, 20..23 = kt8(tail)
  __shared__ float xl[4][16][20];      // 5 KB, per-wave private region
  int bx = blockIdx.x;
  int s = bx >> 7, c = bx & 127;
  int tid = threadIdx.x;
  int w = tid >> 6, lane = tid & 63;
  int lq = lane >> 4, ln = lane & 15;

  const uint4* wg = (const uint4*)(Wg + (size_t)(s * CC + c) * WELEM);

  // stage Wl: main kt3..7 (swizzled) + tail kt8 (flat)
  for (int d = tid; d < 1280; d += 256) {
    int n = d / 20, j = d % 20;                // j = (kt-3)*4 + lqj
    int kt = 3 + (j >> 2), lqj = j & 3;
    int span = (kt - 3) * 4 + (n >> 4);
    int pos = (lqj * 16 + (n & 15)) ^ (kt & 7);
    Wl4[span * 64 + pos] = wg[n * 32 + 12 + j];
  }
  {
    int d = tid;  // 256 uint4 tail, 1 per thread
    Wl4[1280 + d] = wg[2048 + d];
  }
  // reg-cache B for kt0..2 (per-lane fragment, 12 uint4)
  uint4 Bc[12];
  #pragma unroll
  for (int kt = 0; kt < 3; kt++)
    #pragma unroll
    for (int nt = 0; nt < 4; nt++)
      Bc[kt * 4 + nt] = wg[(nt * 16 + ln) * 32 + kt * 4 + lq];

  int s0 = seg[s], s1 = seg[s + 1];
  __syncthreads();  // the only barrier

  for (int base = s0; base < s1; base += 64) {
    // per-wave x staging: lane (lq,ln) loads row ln, chunk lq
    int row = base + w * 16 + ln;
    int sval = (row < s1) ? sorted[row] : sorted[s0];
    float4 xc = *((const float4*)(xg + ((size_t)sval * CC + c) * 16) + lq);
    *(float4*)(&xl[w][ln][lq * 4]) = xc;
    // own row for A-build (compiler inserts lgkmcnt wait)
    float xv[16];
    #pragma unroll
    for (int q = 0; q < 4; q++) {
      float4 v = *(const float4*)(&xl[w][ln][q * 4]);
      xv[q * 4] = v.x; xv[q * 4 + 1] = v.y; xv[q * 4 + 2] = v.z; xv[q * 4 + 3] = v.w;
    }
    // lq-dependent l-half, hoisted once
    float xs8[8];
    #pragma unroll
    for (int t = 0; t < 8; t++) xs8[t] = (lq & 1) ? xv[8 + t] : xv[t];

    f32x4 acc[4];
    #pragma unroll
    for (int nt = 0; nt < 4; nt++) acc[nt] = (f32x4){0.f, 0.f, 0.f, 0.f};

    #pragma unroll
    for (int kt = 0; kt < 9; kt++) {
      uint4 av;
      if (kt < 8) {
        float xj = (lq & 2) ? xv[kt * 2 + 1] : xv[kt * 2];
        av.x = pk2(xj * xs8[0], xj * xs8[1]);
        av.y = pk2(xj * xs8[2], xj * xs8[3]);
        av.z = pk2(xj * xs8[4], xj * xs8[5]);
        av.w = pk2(xj * xs8[6], xj * xs8[7]);
      } else {
        av.x = pk2(xs8[0], xs8[1]);
        av.y = pk2(xs8[2], xs8[3]);
        av.z = pk2(xs8[4], xs8[5]);
        av.w = pk2(xs8[6], xs8[7]);
        if (lq == 2) av = make_uint4(0x3f80u, 0u, 0u, 0u);  // the constant-1 column (k=272)
        if (lq == 3) av = make_uint4(0u, 0u, 0u, 0u);
      }
      bf16x8 a = *(bf16x8*)&av;
      #pragma unroll
      for (int nt = 0; nt < 4; nt++) {
        uint4 bv;
        if (kt < 3) {
          bv = Bc[kt * 4 + nt];
        } else if (kt < 8) {
          bv = Wl4[((kt - 3) * 4 + nt) * 64 + (lane ^ (kt & 7))];
        } else {
          bv = Wl4[1280 + nt * 64 + lane];
        }
        bf16x8 b = *(bf16x8*)&bv;
        acc[nt] = __builtin_amdgcn_mfma_f32_16x16x32_bf16(a, b, acc[nt], 0, 0, 0);
      }
    }
    // epilogue: y[b][o] = sum_i D[m][(o,i)] * x[m][i];  C/D: row=lq*4+r, col=ln
    float xr[4];
    #pragma unroll
    for (int r = 0; r < 4; r++) xr[r] = xl[w][lq * 4 + r][ln];
    #pragma unroll
    for (int nt = 0; nt < 4; nt++) {
      #pragma unroll
      for (int r = 0; r < 4; r++) {
        float v = acc[nt][r] * xr[r];
        v += __shfl_xor(v, 1, 64);
        v += __shfl_xor(v, 2, 64);
        v += __shfl_xor(v, 4, 64);
        v += __shfl_xor(v, 8, 64);
        int m = lq * 4 + r;
        if (ln == m && (base + w * 16 + m) < s1) {
          y[((size_t)sval * CC + c) * 4 + nt] = v;  // lane ln==m holds sorted[row m]
        }
      }
    }
  }
}

// ============ lin_kernel: channel-mixing linear + pack ============
// grid 1024 (one node each) x 128 threads (n)
__global__ __launch_bounds__(128) void lin_kernel(
    const float* __restrict__ y, const float* __restrict__ w_lin,
    float* __restrict__ out) {
  int b = blockIdx.x;
  int n = threadIdx.x;
  const float4* yb4 = (const float4*)(y + (size_t)b * 512);
  float a0 = 0.f, a1 = 0.f, a2 = 0.f, a3 = 0.f;
  #pragma unroll 8
  for (int cc = 0; cc < CC; cc++) {
    float4 yv = yb4[cc];                        // uniform broadcast
    float wl0 = w_lin[(size_t)cc * CC + n];     // g=0
    float wl1 = w_lin[16384 + (size_t)cc * CC + n];
    a0 = fmaf(yv.x, wl0, a0);
    a1 = fmaf(yv.y, wl1, a1);
    a2 = fmaf(yv.z, wl1, a2);
    a3 = fmaf(yv.w, wl1, a3);
  }
  const float scale = 0.08838834764831845f;  // 1/sqrt(128)
  out[(size_t)b * 512 + n] = a0 * scale;
  out[(size_t)b * 512 + 128 + (size_t)n * 3 + 0] = a1 * scale;
  out[(size_t)b * 512 + 128 + (size_t)n * 3 + 1] = a2 * scale;
  out[(size_t)b * 512 + 128 + (size_t)n * 3 + 2] = a3 * scale;
}

extern "C" void kernel_launch(void* const* d_in, const int* in_sizes, int n_in,
                              void* d_out, int out_size, void* d_ws, size_t ws_size,
                              hipStream_t stream) {
  const float* node_feats = (const float*)d_in[0];
  const float* u3_0 = (const float*)d_in[1];
  const float* u3_1 = (const float*)d_in[2];
  const float* u2_0 = (const float*)d_in[3];
  const float* u2_1 = (const float*)d_in[4];
  const float* u1_0 = (const float*)d_in[5];
  const float* u1_1 = (const float*)d_in[6];
  const float* w3   = (const float*)d_in[7];
  const float* w2   = (const float*)d_in[8];
  const float* w1   = (const float*)d_in[9];
  const float* wlin = (const float*)d_in[10];
  const int* species = (const int*)d_in[11];
  float* out = (float*)d_out;

  char* ws = (char*)d_ws;
  ushort* W  = (ushort*)ws;                  // 512*18432*2 = 18,874,368 B
  float* yb  = (float*)(ws + 18874368);      //  2,097,152 B
  int* sorted = (int*)(ws + 20971520);       //      4,096 B
  int* seg    = (int*)(ws + 20975616);       //         32 B

  pre_kernel<<<1025, 256, 0, stream>>>(u3_0, u3_1, w3, u2_0, u2_1, u1_0, u1_1,
                                       w2, w1, species, W, sorted, seg);
  corr_kernel<<<512, 256, 0, stream>>>(node_feats, W, sorted, seg, yb);
  lin_kernel<<<1024, 128, 0, stream>>>(yb, wlin, out);
}